// Round 7
// baseline (570.483 us; speedup 1.0000x reference)
//
#include <hip/hip_runtime.h>
#include <hip/hip_fp16.h>

// Problem constants
#define OOv   200
#define KKv   1600
#define OPAD  208             // 13 col-tiles of 16
#define NCHUNK 50             // K=32 chunks
#define CHUNK_BYTES 13312     // one K=32 chunk of W-fp16 (208*4 slots * 16B)
#define XSTR 40               // halfs per x row (80 B, mult of 16)
#define YSTR 56               // halfs per y row (112 B; 28-dw stride = 2-way banks, free)
#define ROWS 128              // rows per block (restored: intensity > occupancy-via-shrink)

typedef _Float16 half8  __attribute__((ext_vector_type(8)));
typedef _Float16 half2v __attribute__((ext_vector_type(2)));
typedef __attribute__((ext_vector_type(4))) float floatx4;

// ---------------------------------------------------------------------------
// Pre-kernel: W [200][1600] fp32 -> Wh fp16, K-chunk-major, 16B-slot swizzled.
// idx = c*6656 + slot*8 + j ; slot = o*4 + (kg ^ ((o>>1)&3)) ; k = c*32+kg*8+j
// ---------------------------------------------------------------------------
__global__ void wb_convert_kernel(const float* __restrict__ W,
                                  unsigned short* __restrict__ Wh) {
    int idx = blockIdx.x * 256 + threadIdx.x;
    if (idx >= NCHUNK * OPAD * 32) return;     // 332800
    int j    = idx & 7;
    int slot = (idx >> 3) % (OPAD * 4);
    int c    = (idx >> 3) / (OPAD * 4);
    int o    = slot >> 2;
    int kgs  = slot & 3;
    int kg   = kgs ^ ((o >> 1) & 3);
    int k    = c * 32 + kg * 8 + j;
    float v  = (o < OOv) ? W[o * KKv + k] : 0.0f;
    union { _Float16 h; unsigned short u; } cv; cv.h = (_Float16)v;
    Wh[idx] = cv.u;
}

// ---------------------------------------------------------------------------
// One K=32 step, barrier-free, single-buffered, rt=4, ct=NT (4 or 3).
//  (a) NT global_load_dwordx4 of W fragments (Wh L2-resident; co-resident
//      blocks + rowhalf twin read the same bytes -> L1/L2 reuse)
//  (b) af build: 1 cndmask'd y-base + 4 ds_read_b128 (imm offsets) + pk muls
//  (c) MFMA cluster under setprio(1)
// 4 free-running waves/SIMD: each wave's load-wait chain (~600-800 cyc) is
// covered by ~3x310 cyc of the other waves' MFMA issue (round-6 lesson:
// 2 waves could not cover it; shrinking the tile to gain waves halved
// intensity and lost more than it gained -- this keeps rt=4).
// ---------------------------------------------------------------------------
template<int NT, int P>
__device__ __forceinline__ void gstep(
        const char* wg,                    // Wh + g*10*CHUNK_BYTES (uniform)
        int bfoff,
        const char* yb,                    // ylds + rowb*112 + kg*16
        half8 (&xq)[4],
        bool w1, bool w2, bool w3,
        floatx4 (&acc)[4][4])
{
    constexpr int R32a[5] = {0, 64, 48, 32, 16};  // (32p mod 40) in bytes
    constexpr int B5a[5]  = {0, 0, 1, 2, 3};
    constexpr int WKa[5]  = {0, 1, 2, 3, 0};
    constexpr int pm = P % 5, pd = P / 5;
    constexpr int yimm  = R32a[pm];
    constexpr int dbase = B5a[pm] + 4 * pd;
    constexpr int wk    = WKa[pm];
    const bool use = (wk == 1) ? w1 : (wk == 2) ? w2 : (wk == 3) ? w3 : false;

    // (a) B-fragments straight from global (L1/L2-hot)
    half8 bf[NT];
#pragma unroll
    for (int ct = 0; ct < NT; ++ct)
        bf[ct] = *(const half8*)(wg + (size_t)P * CHUNK_BYTES + bfoff + ct * 1024);

    // (b) A-fragments: af[rt] = broadcast(x elem) * y window
    //     single runtime base (cndmask) + compile-time rt*1792 offsets
    const char* ya = yb + (yimm - (use ? 80 : 0));   // >=0 by kg>=wk
    half8 af[4];
#pragma unroll
    for (int rt = 0; rt < 4; ++rt) {
        half8 yv = *(const half8*)(ya + rt * 1792);  // 16 rows * 112 B
        _Float16 e;
        if constexpr (wk == 0) {
            e = xq[rt][dbase];             // use==false at compile time
        } else {
            e = use ? xq[rt][dbase + 1] : xq[rt][dbase];
        }
        half8 xsp = {e, e, e, e, e, e, e, e};
        af[rt] = xsp * yv;
    }

    // (c) MFMA cluster
    __builtin_amdgcn_s_setprio(1);
#pragma unroll
    for (int ct = 0; ct < NT; ++ct)
#pragma unroll
        for (int rt = 0; rt < 4; ++rt)
            acc[rt][ct] = __builtin_amdgcn_mfma_f32_16x16x32_f16(
                af[rt], bf[ct], acc[rt][ct], 0, 0, 0);
    __builtin_amdgcn_s_setprio(0);
}

template<int NT>
__device__ __forceinline__ void kloop(
        const char* wb, int bfoff,
        const char* yb, const char* xb,
        bool w1, bool w2, bool w3,
        floatx4 (&acc)[4][4])
{
#pragma unroll 1
    for (int g = 0; g < 5; ++g) {
        // x window for this group: elements 8g..8g+7 per row, rt*1280 strided
        half8 xq[4];
#pragma unroll
        for (int rt = 0; rt < 4; ++rt)
            xq[rt] = *(const half8*)(xb + g * 16 + rt * 1280);
        const char* wg = wb + (size_t)g * 10 * CHUNK_BYTES;
        gstep<NT, 0>(wg, bfoff, yb, xq, w1, w2, w3, acc);
        gstep<NT, 1>(wg, bfoff, yb, xq, w1, w2, w3, acc);
        gstep<NT, 2>(wg, bfoff, yb, xq, w1, w2, w3, acc);
        gstep<NT, 3>(wg, bfoff, yb, xq, w1, w2, w3, acc);
        gstep<NT, 4>(wg, bfoff, yb, xq, w1, w2, w3, acc);
        gstep<NT, 5>(wg, bfoff, yb, xq, w1, w2, w3, acc);
        gstep<NT, 6>(wg, bfoff, yb, xq, w1, w2, w3, acc);
        gstep<NT, 7>(wg, bfoff, yb, xq, w1, w2, w3, acc);
        gstep<NT, 8>(wg, bfoff, yb, xq, w1, w2, w3, acc);
        gstep<NT, 9>(wg, bfoff, yb, xq, w1, w2, w3, acc);
    }
}

// ---------------------------------------------------------------------------
// Main kernel: 512 blocks x 512 thr (8 waves), 128 rows x 208 cols per block.
// Waves: rowhalf = wave&1 (64 rows, rt=4), colgrp = wave>>1 in 0..3 owning
// 4/3/3/3 col-tiles (obase 0/64/112/160). acc[4][4] = 64 AGPR; launch_bounds
// (512,4) caps 128 regs/wave -> 2 blocks/CU = 4 waves/SIMD. W streamed from
// L1/L2 per step (Wh = 0.67 MB, L2-resident). K-loop has ZERO barriers.
// ---------------------------------------------------------------------------
__global__ __launch_bounds__(512, 4) void cin_mfma_kernel(
        const float* __restrict__ X, const float* __restrict__ Y,
        const unsigned short* __restrict__ Wh, float* __restrict__ Out) {
    __shared__ __align__(16) _Float16 xlds[ROWS * XSTR];           // 10240
    __shared__ __align__(16) _Float16 ylds[ROWS * YSTR];           // 14336

    const int tid     = threadIdx.x;
    const int wave    = tid >> 6;
    const int lane    = tid & 63;
    const int li      = lane & 15;
    const int kg      = lane >> 4;
    const int rowhalf = wave & 1;          // 64-row half
    const int colgrp  = wave >> 1;         // 0..3 -> 4/3/3/3 col-tiles
    const int ntiles  = colgrp ? 3 : 4;
    const int tbase   = colgrp ? (1 + colgrp * 3) : 0;   // 0,4,7,10
    const int obase   = tbase * 16;                      // 0,64,112,160
    const long blockbase = (long)blockIdx.x * ROWS;

    // ---- prologue: stage x,y (128 rows x 40) as fp16
    const float* xg = X + blockbase * 40;
    const float* yg = Y + blockbase * 40;
    for (int i = tid; i < 1280; i += 512) {
        int r  = i / 10;
        int c4 = (i % 10) * 4;                 // 40 % 4 == 0: row-aligned
        floatx4 vx = *(const floatx4*)(xg + i * 4);
        floatx4 vy = *(const floatx4*)(yg + i * 4);
        union { half2v h[2]; unsigned long long u; } px, py;
        px.h[0] = (half2v){(_Float16)vx.x, (_Float16)vx.y};
        px.h[1] = (half2v){(_Float16)vx.z, (_Float16)vx.w};
        py.h[0] = (half2v){(_Float16)vy.x, (_Float16)vy.y};
        py.h[1] = (half2v){(_Float16)vy.z, (_Float16)vy.w};
        *(unsigned long long*)(xlds + r * XSTR + c4) = px.u;
        *(unsigned long long*)(ylds + r * YSTR + c4) = py.u;
    }
    __syncthreads();    // the ONLY barrier

    floatx4 acc[4][4];
#pragma unroll
    for (int rt = 0; rt < 4; ++rt)
#pragma unroll
        for (int ct = 0; ct < 4; ++ct)
            acc[rt][ct] = (floatx4){0.f, 0.f, 0.f, 0.f};

    const int rowb = rowhalf * 64 + li;
    const char* yb = (const char*)ylds + rowb * (YSTR * 2) + kg * 16;
    const char* xb = (const char*)xlds + rowb * (XSTR * 2);
    const bool w1 = kg >= 1, w2 = kg >= 2, w3 = kg >= 3;

    // per-lane B-frag byte offset inside a global W chunk (16B-slot swizzle)
    const int bfoff = (obase + li) * 64 + ((kg ^ ((li >> 1) & 3)) * 16);

    const char* wb = (const char*)Wh;

    if (colgrp == 0)
        kloop<4>(wb, bfoff, yb, xb, w1, w2, w3, acc);
    else
        kloop<3>(wb, bfoff, yb, xb, w1, w2, w3, acc);

    // ---- epilogue: C/D layout col = lane&15, row = (lane>>4)*4 + reg  [m89]
#pragma unroll
    for (int rt = 0; rt < 4; ++rt) {
#pragma unroll
        for (int ct = 0; ct < 4; ++ct) {
            if (ct >= ntiles) continue;
            int gcol = obase + ct * 16 + li;
            if (gcol < OOv) {
#pragma unroll
                for (int r4 = 0; r4 < 4; ++r4) {
                    long grow = blockbase + rowhalf * 64 + rt * 16 + kg * 4 + r4;
                    Out[grow * OOv + gcol] = acc[rt][ct][r4];
                }
            }
        }
    }
}

extern "C" void kernel_launch(void* const* d_in, const int* in_sizes, int n_in,
                              void* d_out, int out_size, void* d_ws, size_t ws_size,
                              hipStream_t stream) {
    (void)in_sizes; (void)n_in; (void)out_size; (void)ws_size;
    const float* X = (const float*)d_in[0];
    const float* Y = (const float*)d_in[1];
    const float* W = (const float*)d_in[2];
    float* Out = (float*)d_out;
    unsigned short* Wh = (unsigned short*)d_ws;   // 665,600 B scratch

    wb_convert_kernel<<<1300, 256, 0, stream>>>(W, Wh);
    cin_mfma_kernel<<<512, 512, 0, stream>>>(X, Y, Wh, Out);
}

// Round 8
// 117.753 us; speedup vs baseline: 4.8447x; 4.8447x over previous
//
#include <hip/hip_runtime.h>
#include <hip/hip_fp16.h>

// Problem constants
#define OOv   200
#define KKv   1600
#define OPAD  208             // 13 col-tiles of 16
#define NCHUNK 50             // K=32 chunks
#define CHUNK_BYTES 13312     // one K=32 chunk of W-fp16 (208*4 slots * 16B)
#define XSTR 40               // halfs per x row (80 B, mult of 16)
#define YSTR 56               // halfs per y row (112 B; 28-dw stride = 2-way banks, free)
#define ROWS 128              // rows per block

typedef _Float16 half8  __attribute__((ext_vector_type(8)));
typedef _Float16 half2v __attribute__((ext_vector_type(2)));
typedef __attribute__((ext_vector_type(4))) float floatx4;

// ---------------------------------------------------------------------------
// Pre-kernel: W [200][1600] fp32 -> Wh fp16, K-chunk-major, 16B-slot swizzled.
// idx = c*6656 + slot*8 + j ; slot = o*4 + (kg ^ ((o>>1)&3)) ; k = c*32+kg*8+j
// ---------------------------------------------------------------------------
__global__ void wb_convert_kernel(const float* __restrict__ W,
                                  unsigned short* __restrict__ Wh) {
    int idx = blockIdx.x * 256 + threadIdx.x;
    if (idx >= NCHUNK * OPAD * 32) return;     // 332800
    int j    = idx & 7;
    int slot = (idx >> 3) % (OPAD * 4);
    int c    = (idx >> 3) / (OPAD * 4);
    int o    = slot >> 2;
    int kgs  = slot & 3;
    int kg   = kgs ^ ((o >> 1) & 3);
    int k    = c * 32 + kg * 8 + j;
    float v  = (o < OOv) ? W[o * KKv + k] : 0.0f;
    union { _Float16 h; unsigned short u; } cv; cv.h = (_Float16)v;
    Wh[idx] = cv.u;
}

// ---------------------------------------------------------------------------
// One K=32 step, barrier-free, REGISTER double-buffered (the round-4 scheme,
// now with the register budget to support it: launch_bounds(512,2) -> 256
// regs/wave; acc[4][4]=64 AGPR + ~125 arch incl bfA+bfB leaves ~65 slack).
//  (a) prefetch chunk c+1's NT fragments into nxt (L1/L2-hot Wh)
//  (b) af build (y ds_read + x broadcast-mul)
//  (c) MFMA cluster on cur (prefetched LAST step -> its ~200-300 cyc L1/L2
//      latency hid under the previous step's ~310 cyc MFMA burst)
// ---------------------------------------------------------------------------
template<int NT, int P, bool PREF>
__device__ __forceinline__ void gstep(
        const char* wg,                    // Wh + g*10*CHUNK_BYTES (uniform)
        int bfoff,
        const char* yb,                    // ylds + rowb*112 + kg*16
        half8 (&xq)[4],
        bool w1, bool w2, bool w3,
        half8 (&cur)[NT], half8 (&nxt)[NT],
        floatx4 (&acc)[4][4])
{
    constexpr int R32a[5] = {0, 64, 48, 32, 16};  // (32p mod 40) in bytes
    constexpr int B5a[5]  = {0, 0, 1, 2, 3};
    constexpr int WKa[5]  = {0, 1, 2, 3, 0};
    constexpr int pm = P % 5, pd = P / 5;
    constexpr int yimm  = R32a[pm];
    constexpr int dbase = B5a[pm] + 4 * pd;
    constexpr int wk    = WKa[pm];
    const bool use = (wk == 1) ? w1 : (wk == 2) ? w2 : (wk == 3) ? w3 : false;

    // (a) prefetch chunk c+1 fragments (valid across group boundary: P=9
    //     reads wg+10*CHUNK = first chunk of the next group)
    if constexpr (PREF) {
#pragma unroll
        for (int ct = 0; ct < NT; ++ct)
            nxt[ct] = *(const half8*)(wg + (size_t)(P + 1) * CHUNK_BYTES
                                      + bfoff + ct * 1024);
    }

    // (b) A-fragments: af[rt] = broadcast(x elem) * y window
    const char* ya = yb + (yimm - (use ? 80 : 0));   // >=0 by kg>=wk
    half8 af[4];
#pragma unroll
    for (int rt = 0; rt < 4; ++rt) {
        half8 yv = *(const half8*)(ya + rt * 1792);  // 16 rows * 112 B
        _Float16 e;
        if constexpr (wk == 0) {
            e = xq[rt][dbase];             // use==false at compile time
        } else {
            e = use ? xq[rt][dbase + 1] : xq[rt][dbase];
        }
        half8 xsp = {e, e, e, e, e, e, e, e};
        af[rt] = xsp * yv;
    }

    // (c) MFMA cluster on the PREVIOUSLY prefetched buffer
    __builtin_amdgcn_s_setprio(1);
#pragma unroll
    for (int ct = 0; ct < NT; ++ct)
#pragma unroll
        for (int rt = 0; rt < 4; ++rt)
            acc[rt][ct] = __builtin_amdgcn_mfma_f32_16x16x32_f16(
                af[rt], cur[ct], acc[rt][ct], 0, 0, 0);
    __builtin_amdgcn_s_setprio(0);
}

template<int NT>
__device__ __forceinline__ void kloop(
        const char* wb, int bfoff,
        const char* yb, const char* xb,
        bool w1, bool w2, bool w3,
        floatx4 (&acc)[4][4])
{
    half8 bfA[NT], bfB[NT];
    // preload chunk 0 into bfA
#pragma unroll
    for (int ct = 0; ct < NT; ++ct)
        bfA[ct] = *(const half8*)(wb + bfoff + ct * 1024);

#define GS(PP, PR, CUR, NXT) \
    gstep<NT, PP, PR>(wg, bfoff, yb, xq, w1, w2, w3, CUR, NXT, acc)

#pragma unroll 1
    for (int g = 0; g < 4; ++g) {
        half8 xq[4];
#pragma unroll
        for (int rt = 0; rt < 4; ++rt)
            xq[rt] = *(const half8*)(xb + g * 16 + rt * 1280);
        const char* wg = wb + (size_t)g * 10 * CHUNK_BYTES;
        GS(0, true, bfA, bfB);
        GS(1, true, bfB, bfA);
        GS(2, true, bfA, bfB);
        GS(3, true, bfB, bfA);
        GS(4, true, bfA, bfB);
        GS(5, true, bfB, bfA);
        GS(6, true, bfA, bfB);
        GS(7, true, bfB, bfA);
        GS(8, true, bfA, bfB);
        GS(9, true, bfB, bfA);   // prefetches first chunk of group g+1 -> bfA
    }
    // peeled group 4 (chunks 40..49): last step computes only
    {
        half8 xq[4];
#pragma unroll
        for (int rt = 0; rt < 4; ++rt)
            xq[rt] = *(const half8*)(xb + 4 * 16 + rt * 1280);
        const char* wg = wb + (size_t)4 * 10 * CHUNK_BYTES;
        GS(0, true, bfA, bfB);
        GS(1, true, bfB, bfA);
        GS(2, true, bfA, bfB);
        GS(3, true, bfB, bfA);
        GS(4, true, bfA, bfB);
        GS(5, true, bfB, bfA);
        GS(6, true, bfA, bfB);
        GS(7, true, bfB, bfA);
        GS(8, true, bfA, bfB);
        GS(9, false, bfB, bfA);  // chunk 49: compute only
    }
#undef GS
}

// ---------------------------------------------------------------------------
// Main kernel: 512 blocks x 512 thr (8 waves), 128 rows x 208 cols per block.
// Waves: rowhalf = wave&1 (64 rows, rt=4), colgrp = wave>>1 in 0..3 owning
// 4/3/3/3 col-tiles (obase 0/64/112/160). acc[4][4] = 64 AGPR.
// __launch_bounds__(512,2): 256 regs/wave (round-7 lesson: arch demand is
// ~125-140; the 128-reg cap spilled 1.4 GB of scratch), 1 block/CU,
// 2 waves/SIMD; latency hiding comes from the per-wave register double
// buffer, not TLP. W streamed from L1/L2 (Wh = 0.67 MB, L2-resident).
// K-loop has ZERO barriers.
// ---------------------------------------------------------------------------
__global__ __launch_bounds__(512, 2) void cin_mfma_kernel(
        const float* __restrict__ X, const float* __restrict__ Y,
        const unsigned short* __restrict__ Wh, float* __restrict__ Out) {
    __shared__ __align__(16) _Float16 xlds[ROWS * XSTR];           // 10240
    __shared__ __align__(16) _Float16 ylds[ROWS * YSTR];           // 14336

    const int tid     = threadIdx.x;
    const int wave    = tid >> 6;
    const int lane    = tid & 63;
    const int li      = lane & 15;
    const int kg      = lane >> 4;
    const int rowhalf = wave & 1;          // 64-row half
    const int colgrp  = wave >> 1;         // 0..3 -> 4/3/3/3 col-tiles
    const int ntiles  = colgrp ? 3 : 4;
    const int tbase   = colgrp ? (1 + colgrp * 3) : 0;   // 0,4,7,10
    const int obase   = tbase * 16;                      // 0,64,112,160
    const long blockbase = (long)blockIdx.x * ROWS;

    // ---- prologue: stage x,y (128 rows x 40) as fp16
    const float* xg = X + blockbase * 40;
    const float* yg = Y + blockbase * 40;
    for (int i = tid; i < 1280; i += 512) {
        int r  = i / 10;
        int c4 = (i % 10) * 4;                 // 40 % 4 == 0: row-aligned
        floatx4 vx = *(const floatx4*)(xg + i * 4);
        floatx4 vy = *(const floatx4*)(yg + i * 4);
        union { half2v h[2]; unsigned long long u; } px, py;
        px.h[0] = (half2v){(_Float16)vx.x, (_Float16)vx.y};
        px.h[1] = (half2v){(_Float16)vx.z, (_Float16)vx.w};
        py.h[0] = (half2v){(_Float16)vy.x, (_Float16)vy.y};
        py.h[1] = (half2v){(_Float16)vy.z, (_Float16)vy.w};
        *(unsigned long long*)(xlds + r * XSTR + c4) = px.u;
        *(unsigned long long*)(ylds + r * YSTR + c4) = py.u;
    }
    __syncthreads();    // the ONLY barrier

    floatx4 acc[4][4];
#pragma unroll
    for (int rt = 0; rt < 4; ++rt)
#pragma unroll
        for (int ct = 0; ct < 4; ++ct)
            acc[rt][ct] = (floatx4){0.f, 0.f, 0.f, 0.f};

    const int rowb = rowhalf * 64 + li;
    const char* yb = (const char*)ylds + rowb * (YSTR * 2) + kg * 16;
    const char* xb = (const char*)xlds + rowb * (XSTR * 2);
    const bool w1 = kg >= 1, w2 = kg >= 2, w3 = kg >= 3;

    // per-lane B-frag byte offset inside a global W chunk (16B-slot swizzle)
    const int bfoff = (obase + li) * 64 + ((kg ^ ((li >> 1) & 3)) * 16);

    const char* wb = (const char*)Wh;

    if (colgrp == 0)
        kloop<4>(wb, bfoff, yb, xb, w1, w2, w3, acc);
    else
        kloop<3>(wb, bfoff, yb, xb, w1, w2, w3, acc);

    // ---- epilogue: C/D layout col = lane&15, row = (lane>>4)*4 + reg  [m89]
#pragma unroll
    for (int rt = 0; rt < 4; ++rt) {
#pragma unroll
        for (int ct = 0; ct < 4; ++ct) {
            if (ct >= ntiles) continue;
            int gcol = obase + ct * 16 + li;
            if (gcol < OOv) {
#pragma unroll
                for (int r4 = 0; r4 < 4; ++r4) {
                    long grow = blockbase + rowhalf * 64 + rt * 16 + kg * 4 + r4;
                    Out[grow * OOv + gcol] = acc[rt][ct][r4];
                }
            }
        }
    }
}

extern "C" void kernel_launch(void* const* d_in, const int* in_sizes, int n_in,
                              void* d_out, int out_size, void* d_ws, size_t ws_size,
                              hipStream_t stream) {
    (void)in_sizes; (void)n_in; (void)out_size; (void)ws_size;
    const float* X = (const float*)d_in[0];
    const float* Y = (const float*)d_in[1];
    const float* W = (const float*)d_in[2];
    float* Out = (float*)d_out;
    unsigned short* Wh = (unsigned short*)d_ws;   // 665,600 B scratch

    wb_convert_kernel<<<1300, 256, 0, stream>>>(W, Wh);
    cin_mfma_kernel<<<512, 512, 0, stream>>>(X, Y, Wh, Out);
}